// Round 6
// baseline (255.250 us; speedup 1.0000x reference)
//
#include <hip/hip_runtime.h>

// B=4, L=2048, D=768, H=12, dk=64.  All heavy math in bf16 MFMA 16x16x32.
// ws layout (shorts): Qbf,Kbf,Qh,Ks,Vs (6291456 each), Wbf (1769472),
// attnw aliases Qbf (dead after proj). ~63.5 MiB total.
// Vs: [n][l/4][d][4]        (proj writes 128B-contiguous; attn reads uint2)
// Ks: [n][l/16][d/8][16][8] fragment-major (attn A-frag = 16B/lane coalesced)

using s16x8 = __attribute__((ext_vector_type(8))) short;
using u16x4 = __attribute__((ext_vector_type(4))) unsigned short;
using f32x4 = __attribute__((ext_vector_type(4))) float;

#define MFMA32(a, b, c) __builtin_amdgcn_mfma_f32_16x16x32_bf16((a), (b), (c), 0, 0, 0)

constexpr float QSCALE = 0.125f * 1.44269504088896340736f;  // 1/sqrt(64) * log2(e)
constexpr float NEG_FILL_S = -1.0e10f;                      // exp2(s+this) == 0

__device__ __forceinline__ unsigned int cvtpk(float a, float b) {
  unsigned int d;
  asm("v_cvt_pk_bf16_f32 %0, %1, %2" : "=v"(d) : "v"(a), "v"(b));
  return d;
}
__device__ __forceinline__ u16x4 pack4(float x0, float x1, float x2, float x3) {
  union { unsigned int d[2]; u16x4 v; } u;
  u.d[0] = cvtpk(x0, x1);
  u.d[1] = cvtpk(x2, x3);
  return u.v;
}
__device__ __forceinline__ unsigned short f2bf(float f) {
  union { float f; unsigned int u; } v; v.f = f;
  return (unsigned short)((v.u + 0x7FFFu + ((v.u >> 16) & 1u)) >> 16);
}
__device__ __forceinline__ float bf2f(unsigned short s) {
  union { unsigned int u; float f; } v; v.u = ((unsigned int)s) << 16;
  return v.f;
}
__device__ __forceinline__ void gll16(const void* g, void* l) {
  __builtin_amdgcn_global_load_lds(
      (const __attribute__((address_space(1))) unsigned int*)g,
      (__attribute__((address_space(3))) unsigned int*)l, 16, 0, 0);
}

// ---------------------------------------------------------------------------
// Prepass: query/key -> bf16 copies + masks.
// qmask = 0/1 (epilogue multiplier); kmaskF = additive fill (0 or -1e10).
// ---------------------------------------------------------------------------
__global__ __launch_bounds__(192) void prepass(
    const float* __restrict__ query, const float* __restrict__ key,
    unsigned short* __restrict__ Qbf, unsigned short* __restrict__ Kbf,
    float* __restrict__ qmask, float* __restrict__ kmaskF) {
  const int row = blockIdx.x, tid = threadIdx.x;
  const int isK = blockIdx.y;
  const float* __restrict__ src = isK ? key : query;
  unsigned short* __restrict__ dst = isK ? Kbf : Qbf;
  const size_t base = (size_t)row * 768 + tid * 4;
  float4 v = *(const float4*)&src[base];
  *(u16x4*)&dst[base] = pack4(v.x, v.y, v.z, v.w);
  float s = (v.x + v.y) + (v.z + v.w);
#pragma unroll
  for (int off = 1; off < 64; off <<= 1) s += __shfl_xor(s, off);
  __shared__ float ws[3];
  if ((tid & 63) == 0) ws[tid >> 6] = s;
  __syncthreads();
  if (tid == 0) {
    float t = ws[0] + ws[1] + ws[2];
    if (isK)
      kmaskF[row] = (t != 0.0f) ? 0.0f : NEG_FILL_S;
    else
      qmask[row] = (t != 0.0f) ? 1.0f : 0.0f;
  }
}

// ---------------------------------------------------------------------------
// Weights -> bf16 (3 x 768x768).
// ---------------------------------------------------------------------------
__global__ __launch_bounds__(256) void convw(
    const float* __restrict__ Wq, const float* __restrict__ Wk,
    const float* __restrict__ Wv, unsigned short* __restrict__ Wbf) {
  const float* __restrict__ W = (blockIdx.y == 0) ? Wq : (blockIdx.y == 1) ? Wk : Wv;
  const size_t idx = ((size_t)blockIdx.x * 256 + threadIdx.x) * 4;
  float4 v = *(const float4*)&W[idx];
  *(u16x4*)&Wbf[(size_t)blockIdx.y * 589824 + idx] = pack4(v.x, v.y, v.z, v.w);
}

// ---------------------------------------------------------------------------
// QKV projection: relu(X@W^T + b). bf16 in, bf16 out.
// 128x64 tile, BK=64, double-buffered global_load_lds, XOR-swizzled reads.
// GRID = 2304: 3 z * (64 m-tiles * 12 n-tiles).   (R3 bug: was 1152 = half M)
// z=0 -> Qh[n][l][d] (scaled); z=1 -> Ks frag-major; z=2 -> Vs packed.
// ---------------------------------------------------------------------------
__global__ __launch_bounds__(256, 3) void proj_qkv(
    const unsigned short* __restrict__ Qbf, const unsigned short* __restrict__ Kbf,
    const unsigned short* __restrict__ Wbf,
    const float* __restrict__ bq, const float* __restrict__ bk,
    const float* __restrict__ bv,
    unsigned short* __restrict__ Qh, unsigned short* __restrict__ Ks,
    unsigned short* __restrict__ Vs) {
  // bijective XCD swizzle over 2304 blocks (288/XCD).
  const int lin = blockIdx.x;
  const int swz = (lin & 7) * 288 + (lin >> 3);
  const int z = swz / 768;
  const int rem = swz - z * 768;
  const int m0 = (rem / 12) * 128, n0 = (rem % 12) * 64;
  const unsigned short* __restrict__ A = (z == 0) ? Qbf : Kbf;
  const unsigned short* __restrict__ W = Wbf + (size_t)z * 589824;
  const float* __restrict__ bias = (z == 0) ? bq : (z == 1) ? bk : bv;

  __shared__ unsigned short Al[2][128][64];
  __shared__ unsigned short Bl[2][64][64];

  const int tid = threadIdx.x, lane = tid & 63, wave = tid >> 6;
  const int wm = wave >> 1, wn = wave & 1;
  const int lx = lane & 15, lg = lane >> 4;
  const int sw = lx & 7;

  f32x4 acc[4][2] = {};

  auto stage = [&](int buf, int kt) {
#pragma unroll
    for (int i = 0; i < 4; ++i) {
      const int c = tid + i * 256;        // 16B chunk id, 1024 per A-tile
      const int r = c >> 3, cc = c & 7;
      const int scol = kt + ((cc ^ (r & 7)) << 3);
      gll16(&A[(size_t)(m0 + r) * 768 + scol],
            &Al[buf][0][0] + ((size_t)(i * 256 + wave * 64)) * 8);
    }
#pragma unroll
    for (int i = 0; i < 2; ++i) {
      const int c = tid + i * 256;        // 512 chunks per B-tile
      const int r = c >> 3, cc = c & 7;
      const int scol = kt + ((cc ^ (r & 7)) << 3);
      gll16(&W[(size_t)(n0 + r) * 768 + scol],
            &Bl[buf][0][0] + ((size_t)(i * 256 + wave * 64)) * 8);
    }
  };

  stage(0, 0);
  asm volatile("s_waitcnt vmcnt(0)" ::: "memory");
  __syncthreads();
  for (int t = 0; t < 12; ++t) {
    if (t < 11) stage((t + 1) & 1, (t + 1) * 64);
    const int buf = t & 1;
#pragma unroll
    for (int kb = 0; kb < 2; ++kb) {
      s16x8 af[4], bfr[2];
#pragma unroll
      for (int i = 0; i < 4; ++i)
        af[i] = *(const s16x8*)&Al[buf][wm * 64 + i * 16 + lx][((kb * 4 + lg) ^ sw) << 3];
#pragma unroll
      for (int j = 0; j < 2; ++j)
        bfr[j] = *(const s16x8*)&Bl[buf][wn * 32 + j * 16 + lx][((kb * 4 + lg) ^ sw) << 3];
#pragma unroll
      for (int i = 0; i < 4; ++i)
#pragma unroll
        for (int j = 0; j < 2; ++j)
          acc[i][j] = MFMA32(af[i], bfr[j], acc[i][j]);
    }
    asm volatile("s_waitcnt vmcnt(0)" ::: "memory");
    __syncthreads();
  }

  // Epilogue. C-frag: col = lane&15 (feature e), row = (lane>>4)*4+r (seq m).
  const float scale = (z == 0) ? QSCALE : 1.0f;
#pragma unroll
  for (int fm = 0; fm < 4; ++fm) {
#pragma unroll
    for (int fn = 0; fn < 2; ++fn) {
      const int e = n0 + wn * 32 + fn * 16 + lx;
      const int hh = e >> 6, d = e & 63;
      const int mg = m0 + wm * 64 + fm * 16 + (lg << 2);
      const int bb = mg >> 11, l = mg & 2047;
      const int nn = hh * 4 + bb;
      const float bv_ = bias[e];
      if (z == 2) {
        // Vs[n][l/4][d][4]: 8B per lane, 128B contiguous across lx
        *(u16x4*)&Vs[(((size_t)nn * 512 + (l >> 2)) * 64 + d) * 4] =
            pack4(fmaxf(acc[fm][fn][0] + bv_, 0.0f), fmaxf(acc[fm][fn][1] + bv_, 0.0f),
                  fmaxf(acc[fm][fn][2] + bv_, 0.0f), fmaxf(acc[fm][fn][3] + bv_, 0.0f));
      } else if (z == 1) {
        // Ks[n][l/16][d/8][16][8]: fragment-major for attn's A-frag loads
#pragma unroll
        for (int r = 0; r < 4; ++r) {
          float vv = fmaxf(acc[fm][fn][r] + bv_, 0.0f);
          Ks[((((size_t)nn * 128 + (l >> 4)) * 8 + (d >> 3)) * 16 + ((l & 12) + r)) * 8 +
             (d & 7)] = f2bf(vv);
        }
      } else {
#pragma unroll
        for (int r = 0; r < 4; ++r) {
          float vv = fmaxf(acc[fm][fn][r] + bv_, 0.0f) * scale;
          Qh[((size_t)(nn * 2048 + l + r)) * 64 + d] = f2bf(vv);
        }
      }
    }
  }
}

// ---------------------------------------------------------------------------
// Flash attention: barrier-free (zero __syncthreads), static-max softmax.
// QK^T: S^T = K.Q^T via 16x16x32, K streamed directly from L2 (frag-major Ks,
//   16B/lane coalesced).  softmax in regs: p = exp2(s + fill), fill from L2.
// PV: via per-wave-PRIVATE PT tile in LDS (rows wave*32..+31) -> only needs
//   wave-local lgkmcnt ordering, no barrier.  V^T A-frags from packed Vs.
// Per-XCD K+V working set = 6 heads * 512KB = 3MB < 4MB L2.
// ---------------------------------------------------------------------------
__global__ __launch_bounds__(256, 3) void attn_fwd(
    const unsigned short* __restrict__ Qh, const unsigned short* __restrict__ Ks,
    const unsigned short* __restrict__ Vs, const float* __restrict__ qmask,
    const float* __restrict__ kmaskF, unsigned short* __restrict__ attnw) {
  const int lin = blockIdx.x;                 // 768 blocks, 96/XCD
  const int swz = (lin & 7) * 96 + (lin >> 3);
  const int n = swz >> 4;
  const int q0 = (swz & 15) * 128;
  const int h = n >> 2, b = n & 3;
  const int tid = threadIdx.x, lane = tid & 63, wave = tid >> 6;
  const int lx = lane & 15, lg = lane >> 4;
  const int sw = lx & 7;

  __shared__ unsigned short PT[128][64];  // swizzled P^T [q][k], per-wave rows

  const int qw = q0 + wave * 32;
  s16x8 qf[2][2];
#pragma unroll
  for (int fq = 0; fq < 2; ++fq)
#pragma unroll
    for (int kb = 0; kb < 2; ++kb)
      qf[fq][kb] = *(const s16x8*)&Qh[((size_t)n * 2048 + qw + fq * 16 + lx) * 64 +
                                      kb * 32 + lg * 8];

  const unsigned short* __restrict__ Ksn = Ks + (size_t)n * 131072;
  const unsigned short* __restrict__ Vsn = Vs + (size_t)n * 131072;
  const float* __restrict__ kfp = kmaskF + b * 2048;

  f32x4 o[4][2] = {};        // O^T acc: [fd][fq], col=q, row=d-local
  float lrun[2] = {0.0f, 0.0f};

  for (int t = 0; t < 32; ++t) {
    const int kt = t * 64;

    // QK^T: S^T[k][q]; K A-frags straight from frag-major Ks (L2-resident)
    f32x4 s[4][2] = {};
#pragma unroll
    for (int fkr = 0; fkr < 4; ++fkr) {
      const int rb = t * 4 + fkr;
      s16x8 kf0 = *(const s16x8*)&Ksn[(size_t)(((rb * 8 + lg) * 16) + lx) * 8];
      s16x8 kf1 = *(const s16x8*)&Ksn[(size_t)(((rb * 8 + 4 + lg) * 16) + lx) * 8];
#pragma unroll
      for (int fq = 0; fq < 2; ++fq) {
        s[fkr][fq] = MFMA32(kf0, qf[fq][0], s[fkr][fq]);
        s[fkr][fq] = MFMA32(kf1, qf[fq][1], s[fkr][fq]);
      }
    }

    // V A-frags hoisted (R3-proven pattern); latency hides under softmax
    uint2 vraw[8][2];
#pragma unroll
    for (int kb = 0; kb < 2; ++kb)
#pragma unroll
      for (int fd = 0; fd < 4; ++fd) {
        const int d = fd * 16 + lx;
        const int g0 = (kt >> 2) + kb * 8 + lg * 2;
        const uint2* vp = (const uint2*)&Vsn[(((size_t)g0) * 64 + d) * 4];
        vraw[kb * 4 + fd][0] = vp[0];
        vraw[kb * 4 + fd][1] = vp[64];  // g0+1
      }

    // additive mask fill (broadcast float4 from L2)
    float4 fl[4];
#pragma unroll
    for (int fkr = 0; fkr < 4; ++fkr)
      fl[fkr] = *(const float4*)&kfp[kt + fkr * 16 + lg * 4];

    // softmax: p = exp2(s + fill); l-accumulate; pack P^T into swizzled LDS
#pragma unroll
    for (int fkr = 0; fkr < 4; ++fkr) {
#pragma unroll
      for (int fq = 0; fq < 2; ++fq) {
        float p0 = __builtin_amdgcn_exp2f(s[fkr][fq][0] + fl[fkr].x);
        float p1 = __builtin_amdgcn_exp2f(s[fkr][fq][1] + fl[fkr].y);
        float p2 = __builtin_amdgcn_exp2f(s[fkr][fq][2] + fl[fkr].z);
        float p3 = __builtin_amdgcn_exp2f(s[fkr][fq][3] + fl[fkr].w);
        lrun[fq] += (p0 + p1) + (p2 + p3);
        const int row = wave * 32 + fq * 16 + lx;
        const int chunk = fkr * 2 + (lg >> 1);
        unsigned short* wp = &PT[row][((chunk ^ sw) << 3) + ((lg & 1) << 2)];
        uint2 pd;
        pd.x = cvtpk(p0, p1);
        pd.y = cvtpk(p2, p3);
        *(uint2*)wp = pd;
      }
    }
    asm volatile("s_waitcnt lgkmcnt(0)" ::: "memory");
    __builtin_amdgcn_sched_barrier(0);

    // PV: O^T[d][q] += V^T[d][lk] * P^T[lk][q]  (wave-private PT rows)
#pragma unroll
    for (int kb = 0; kb < 2; ++kb) {
      s16x8 pf[2];
#pragma unroll
      for (int fq = 0; fq < 2; ++fq)
        pf[fq] = *(const s16x8*)&PT[wave * 32 + fq * 16 + lx][((kb * 4 + lg) ^ sw) << 3];
#pragma unroll
      for (int fd = 0; fd < 4; ++fd) {
        union { uint2 u2[2]; s16x8 v; } vf;
        vf.u2[0] = vraw[kb * 4 + fd][0];
        vf.u2[1] = vraw[kb * 4 + fd][1];
#pragma unroll
        for (int fq = 0; fq < 2; ++fq)
          o[fd][fq] = MFMA32(vf.v, pf[fq], o[fd][fq]);
      }
    }
  }

  // epilogue: l-reduce over lg groups, scale by qmask/l, store bf16
#pragma unroll
  for (int fq = 0; fq < 2; ++fq) {
    lrun[fq] += __shfl_xor(lrun[fq], 16);
    lrun[fq] += __shfl_xor(lrun[fq], 32);
  }
#pragma unroll
  for (int fd = 0; fd < 4; ++fd)
#pragma unroll
    for (int fq = 0; fq < 2; ++fq) {
      const int qg = qw + fq * 16 + lx;
      const float osc = qmask[b * 2048 + qg] / lrun[fq];
      *(u16x4*)&attnw[((size_t)(b * 2048 + qg)) * 768 + h * 64 + fd * 16 + lg * 4] =
          pack4(o[fd][fq][0] * osc, o[fd][fq][1] * osc, o[fd][fq][2] * osc,
                o[fd][fq][3] * osc);
    }
}

// ---------------------------------------------------------------------------
// Residual + LayerNorm (ddof=1), vectorized: 192 threads x float4.
// ---------------------------------------------------------------------------
__global__ __launch_bounds__(192) void ln_kernel(
    const unsigned short* __restrict__ attnw, const float* __restrict__ query,
    const float* __restrict__ gamma, const float* __restrict__ beta,
    float* __restrict__ out) {
  const int row = blockIdx.x, tid = threadIdx.x;
  const size_t base = (size_t)row * 768 + tid * 4;
  u16x4 aw = *(const u16x4*)&attnw[base];
  float4 q = *(const float4*)&query[base];
  float x0 = bf2f(aw[0]) + q.x;
  float x1 = bf2f(aw[1]) + q.y;
  float x2 = bf2f(aw[2]) + q.z;
  float x3 = bf2f(aw[3]) + q.w;
  float s = (x0 + x1) + (x2 + x3);
  float s2 = (x0 * x0 + x1 * x1) + (x2 * x2 + x3 * x3);
#pragma unroll
  for (int off = 1; off < 64; off <<= 1) {
    s += __shfl_xor(s, off);
    s2 += __shfl_xor(s2, off);
  }
  __shared__ float ws[3], ws2[3];
  if ((tid & 63) == 0) { ws[tid >> 6] = s; ws2[tid >> 6] = s2; }
  __syncthreads();
  s = ws[0] + ws[1] + ws[2];
  s2 = ws2[0] + ws2[1] + ws2[2];
  const float mean = s * (1.0f / 768.0f);
  const float var = (s2 - 768.0f * mean * mean) * (1.0f / 767.0f);
  const float rstd = rsqrtf(var + 1e-5f);
  const float4 g = *(const float4*)&gamma[tid * 4];
  const float4 bt = *(const float4*)&beta[tid * 4];
  float4 r;
  r.x = g.x * (x0 - mean) * rstd + bt.x;
  r.y = g.y * (x1 - mean) * rstd + bt.y;
  r.z = g.z * (x2 - mean) * rstd + bt.z;
  r.w = g.w * (x3 - mean) * rstd + bt.w;
  *(float4*)&out[base] = r;
}

// ---------------------------------------------------------------------------
extern "C" void kernel_launch(void* const* d_in, const int* in_sizes, int n_in,
                              void* d_out, int out_size, void* d_ws, size_t ws_size,
                              hipStream_t stream) {
  const float* query = (const float*)d_in[0];
  const float* key = (const float*)d_in[1];
  const float* Wq = (const float*)d_in[2];
  const float* bq = (const float*)d_in[3];
  const float* Wk = (const float*)d_in[4];
  const float* bk = (const float*)d_in[5];
  const float* Wv = (const float*)d_in[6];
  const float* bv = (const float*)d_in[7];
  const float* gamma = (const float*)d_in[8];
  const float* beta = (const float*)d_in[9];
  float* out = (float*)d_out;

  unsigned short* Qbf = (unsigned short*)d_ws;
  unsigned short* Kbf = Qbf + 6291456;
  unsigned short* Qh = Kbf + 6291456;
  unsigned short* Ks = Qh + 6291456;
  unsigned short* Vs = Ks + 6291456;
  unsigned short* Wbf = Vs + 6291456;          // 1769472 shorts
  unsigned short* attnw = Qbf;                 // alias: Qbf dead after proj
  float* qmask = (float*)(Wbf + 1769472);
  float* kmaskF = qmask + 8192;

  convw<<<dim3(576, 3), 256, 0, stream>>>(Wq, Wk, Wv, Wbf);
  prepass<<<dim3(8192, 2), 192, 0, stream>>>(query, key, Qbf, Kbf, qmask, kmaskF);
  proj_qkv<<<2304, 256, 0, stream>>>(Qbf, Kbf, Wbf, bq, bk, bv, Qh, Ks, Vs);
  attn_fwd<<<768, 256, 0, stream>>>(Qh, Ks, Vs, qmask, kmaskF, attnw);
  ln_kernel<<<8192, 192, 0, stream>>>(attnw, query, gamma, beta, out);
}

// Round 7
// 244.437 us; speedup vs baseline: 1.0442x; 1.0442x over previous
//
#include <hip/hip_runtime.h>

// B=4, L=2048, D=768, H=12, dk=64.  All heavy math in bf16 MFMA 16x16x32.
// ws layout (shorts): Qbf,Kbf,Qh,Ks,Vs (6291456 each), Wbf (1769472),
// attnw aliases Qbf (dead after proj). ~63.5 MiB total.
// Vs: [n][l/4][d][4]        (proj writes 128B-contiguous; attn reads uint2)
// Ks: [n][l/16][d/8][16][8] fragment-major (attn A-frag = 16B/lane coalesced)

using s16x8 = __attribute__((ext_vector_type(8))) short;
using u16x4 = __attribute__((ext_vector_type(4))) unsigned short;
using f32x4 = __attribute__((ext_vector_type(4))) float;

#define MFMA32(a, b, c) __builtin_amdgcn_mfma_f32_16x16x32_bf16((a), (b), (c), 0, 0, 0)

constexpr float QSCALE = 0.125f * 1.44269504088896340736f;  // 1/sqrt(64) * log2(e)
constexpr float NEG_FILL_S = -1.0e10f;                      // exp2(s+this) == 0

__device__ __forceinline__ unsigned int cvtpk(float a, float b) {
  unsigned int d;
  asm("v_cvt_pk_bf16_f32 %0, %1, %2" : "=v"(d) : "v"(a), "v"(b));
  return d;
}
__device__ __forceinline__ u16x4 pack4(float x0, float x1, float x2, float x3) {
  union { unsigned int d[2]; u16x4 v; } u;
  u.d[0] = cvtpk(x0, x1);
  u.d[1] = cvtpk(x2, x3);
  return u.v;
}
__device__ __forceinline__ unsigned short f2bf(float f) {
  union { float f; unsigned int u; } v; v.f = f;
  return (unsigned short)((v.u + 0x7FFFu + ((v.u >> 16) & 1u)) >> 16);
}
__device__ __forceinline__ float bf2f(unsigned short s) {
  union { unsigned int u; float f; } v; v.u = ((unsigned int)s) << 16;
  return v.f;
}
__device__ __forceinline__ void gll16(const void* g, void* l) {
  __builtin_amdgcn_global_load_lds(
      (const __attribute__((address_space(1))) unsigned int*)g,
      (__attribute__((address_space(3))) unsigned int*)l, 16, 0, 0);
}

// ---------------------------------------------------------------------------
// Prepass: query/key -> bf16 copies + masks.
// qmask = 0/1 (epilogue multiplier); kmaskF = additive fill (0 or -1e10).
// ---------------------------------------------------------------------------
__global__ __launch_bounds__(192) void prepass(
    const float* __restrict__ query, const float* __restrict__ key,
    unsigned short* __restrict__ Qbf, unsigned short* __restrict__ Kbf,
    float* __restrict__ qmask, float* __restrict__ kmaskF) {
  const int row = blockIdx.x, tid = threadIdx.x;
  const int isK = blockIdx.y;
  const float* __restrict__ src = isK ? key : query;
  unsigned short* __restrict__ dst = isK ? Kbf : Qbf;
  const size_t base = (size_t)row * 768 + tid * 4;
  float4 v = *(const float4*)&src[base];
  *(u16x4*)&dst[base] = pack4(v.x, v.y, v.z, v.w);
  float s = (v.x + v.y) + (v.z + v.w);
#pragma unroll
  for (int off = 1; off < 64; off <<= 1) s += __shfl_xor(s, off);
  __shared__ float ws[3];
  if ((tid & 63) == 0) ws[tid >> 6] = s;
  __syncthreads();
  if (tid == 0) {
    float t = ws[0] + ws[1] + ws[2];
    if (isK)
      kmaskF[row] = (t != 0.0f) ? 0.0f : NEG_FILL_S;
    else
      qmask[row] = (t != 0.0f) ? 1.0f : 0.0f;
  }
}

// ---------------------------------------------------------------------------
// Weights -> bf16 (3 x 768x768).
// ---------------------------------------------------------------------------
__global__ __launch_bounds__(256) void convw(
    const float* __restrict__ Wq, const float* __restrict__ Wk,
    const float* __restrict__ Wv, unsigned short* __restrict__ Wbf) {
  const float* __restrict__ W = (blockIdx.y == 0) ? Wq : (blockIdx.y == 1) ? Wk : Wv;
  const size_t idx = ((size_t)blockIdx.x * 256 + threadIdx.x) * 4;
  float4 v = *(const float4*)&W[idx];
  *(u16x4*)&Wbf[(size_t)blockIdx.y * 589824 + idx] = pack4(v.x, v.y, v.z, v.w);
}

// ---------------------------------------------------------------------------
// QKV projection: relu(X@W^T + b). bf16 in, bf16 out.
// 128x64 tile, BK=64, double-buffered global_load_lds, XOR-swizzled reads.
// GRID = 2304: 3 z * (64 m-tiles * 12 n-tiles).
// z=0 -> Qh[n][l][d] (scaled); z=1 -> Ks frag-major; z=2 -> Vs packed.
// ---------------------------------------------------------------------------
__global__ __launch_bounds__(256, 3) void proj_qkv(
    const unsigned short* __restrict__ Qbf, const unsigned short* __restrict__ Kbf,
    const unsigned short* __restrict__ Wbf,
    const float* __restrict__ bq, const float* __restrict__ bk,
    const float* __restrict__ bv,
    unsigned short* __restrict__ Qh, unsigned short* __restrict__ Ks,
    unsigned short* __restrict__ Vs) {
  // bijective XCD swizzle over 2304 blocks (288/XCD).
  const int lin = blockIdx.x;
  const int swz = (lin & 7) * 288 + (lin >> 3);
  const int z = swz / 768;
  const int rem = swz - z * 768;
  const int m0 = (rem / 12) * 128, n0 = (rem % 12) * 64;
  const unsigned short* __restrict__ A = (z == 0) ? Qbf : Kbf;
  const unsigned short* __restrict__ W = Wbf + (size_t)z * 589824;
  const float* __restrict__ bias = (z == 0) ? bq : (z == 1) ? bk : bv;

  __shared__ unsigned short Al[2][128][64];
  __shared__ unsigned short Bl[2][64][64];

  const int tid = threadIdx.x, lane = tid & 63, wave = tid >> 6;
  const int wm = wave >> 1, wn = wave & 1;
  const int lx = lane & 15, lg = lane >> 4;
  const int sw = lx & 7;

  f32x4 acc[4][2] = {};

  auto stage = [&](int buf, int kt) {
#pragma unroll
    for (int i = 0; i < 4; ++i) {
      const int c = tid + i * 256;        // 16B chunk id, 1024 per A-tile
      const int r = c >> 3, cc = c & 7;
      const int scol = kt + ((cc ^ (r & 7)) << 3);
      gll16(&A[(size_t)(m0 + r) * 768 + scol],
            &Al[buf][0][0] + ((size_t)(i * 256 + wave * 64)) * 8);
    }
#pragma unroll
    for (int i = 0; i < 2; ++i) {
      const int c = tid + i * 256;        // 512 chunks per B-tile
      const int r = c >> 3, cc = c & 7;
      const int scol = kt + ((cc ^ (r & 7)) << 3);
      gll16(&W[(size_t)(n0 + r) * 768 + scol],
            &Bl[buf][0][0] + ((size_t)(i * 256 + wave * 64)) * 8);
    }
  };

  stage(0, 0);
  asm volatile("s_waitcnt vmcnt(0)" ::: "memory");
  __syncthreads();
  for (int t = 0; t < 12; ++t) {
    if (t < 11) stage((t + 1) & 1, (t + 1) * 64);
    const int buf = t & 1;
#pragma unroll
    for (int kb = 0; kb < 2; ++kb) {
      s16x8 af[4], bfr[2];
#pragma unroll
      for (int i = 0; i < 4; ++i)
        af[i] = *(const s16x8*)&Al[buf][wm * 64 + i * 16 + lx][((kb * 4 + lg) ^ sw) << 3];
#pragma unroll
      for (int j = 0; j < 2; ++j)
        bfr[j] = *(const s16x8*)&Bl[buf][wn * 32 + j * 16 + lx][((kb * 4 + lg) ^ sw) << 3];
#pragma unroll
      for (int i = 0; i < 4; ++i)
#pragma unroll
        for (int j = 0; j < 2; ++j)
          acc[i][j] = MFMA32(af[i], bfr[j], acc[i][j]);
    }
    asm volatile("s_waitcnt vmcnt(0)" ::: "memory");
    __syncthreads();
  }

  // Epilogue. C-frag: col = lane&15 (feature e), row = (lane>>4)*4+r (seq m).
  const float scale = (z == 0) ? QSCALE : 1.0f;
#pragma unroll
  for (int fm = 0; fm < 4; ++fm) {
#pragma unroll
    for (int fn = 0; fn < 2; ++fn) {
      const int e = n0 + wn * 32 + fn * 16 + lx;
      const int hh = e >> 6, d = e & 63;
      const int mg = m0 + wm * 64 + fm * 16 + (lg << 2);
      const int bb = mg >> 11, l = mg & 2047;
      const int nn = hh * 4 + bb;
      const float bv_ = bias[e];
      if (z == 2) {
        // Vs[n][l/4][d][4]: 8B per lane, 128B contiguous across lx
        *(u16x4*)&Vs[(((size_t)nn * 512 + (l >> 2)) * 64 + d) * 4] =
            pack4(fmaxf(acc[fm][fn][0] + bv_, 0.0f), fmaxf(acc[fm][fn][1] + bv_, 0.0f),
                  fmaxf(acc[fm][fn][2] + bv_, 0.0f), fmaxf(acc[fm][fn][3] + bv_, 0.0f));
      } else if (z == 1) {
        // Ks[n][l/16][d/8][16][8]: fragment-major for attn's A-frag loads
#pragma unroll
        for (int r = 0; r < 4; ++r) {
          float vv = fmaxf(acc[fm][fn][r] + bv_, 0.0f);
          Ks[((((size_t)nn * 128 + (l >> 4)) * 8 + (d >> 3)) * 16 + ((l & 12) + r)) * 8 +
             (d & 7)] = f2bf(vv);
        }
      } else {
#pragma unroll
        for (int r = 0; r < 4; ++r) {
          float vv = fmaxf(acc[fm][fn][r] + bv_, 0.0f) * scale;
          Qh[((size_t)(nn * 2048 + l + r)) * 64 + d] = f2bf(vv);
        }
      }
    }
  }
}

// ---------------------------------------------------------------------------
// Flash attention: barrier-free, 64 q-rows/WAVE (2-wave blocks of 128 thr).
// __launch_bounds__(128,2) -> 256-VGPR budget: S and O stay in VGPRs (R6's
// VGPR=84 meant AGPR churn through softmax). 4 independent fq chains give
// intra-wave ILP; K/V L2 traffic per output halves vs 32q/wave.
// QK^T: S^T = K.Q^T, K streamed from L2 (frag-major Ks). softmax in regs
// (static max, additive -1e10 fill, exp2). PV via wave-private swizzled PT
// in LDS (wave-local lgkmcnt only, no barrier).
// ---------------------------------------------------------------------------
__global__ __launch_bounds__(128, 2) void attn_fwd(
    const unsigned short* __restrict__ Qh, const unsigned short* __restrict__ Ks,
    const unsigned short* __restrict__ Vs, const float* __restrict__ qmask,
    const float* __restrict__ kmaskF, unsigned short* __restrict__ attnw) {
  const int lin = blockIdx.x;                 // 768 blocks, 96/XCD
  const int swz = (lin & 7) * 96 + (lin >> 3);
  const int n = swz >> 4;
  const int q0 = (swz & 15) * 128;
  const int h = n >> 2, b = n & 3;
  const int tid = threadIdx.x, lane = tid & 63, wave = tid >> 6;  // wave 0..1
  const int lx = lane & 15, lg = lane >> 4;
  const int sw = lx & 7;

  __shared__ unsigned short PT[128][64];  // swizzled P^T [q][k]; wave-private rows

  const int qw = q0 + wave * 64;
  s16x8 qf[4][2];
#pragma unroll
  for (int fq = 0; fq < 4; ++fq)
#pragma unroll
    for (int kb = 0; kb < 2; ++kb)
      qf[fq][kb] = *(const s16x8*)&Qh[((size_t)n * 2048 + qw + fq * 16 + lx) * 64 +
                                      kb * 32 + lg * 8];

  const unsigned short* __restrict__ Ksn = Ks + (size_t)n * 131072;
  const unsigned short* __restrict__ Vsn = Vs + (size_t)n * 131072;
  const float* __restrict__ kfp = kmaskF + b * 2048;

  f32x4 o[4][4] = {};        // O^T acc: [fd][fq], col=q, row=d-local
  float lrun[4] = {0.0f, 0.0f, 0.0f, 0.0f};

  for (int t = 0; t < 32; ++t) {
    const int kt = t * 64;

    // QK^T: S^T[k][q]; K A-frags straight from frag-major Ks (L2-resident)
    f32x4 s[4][4] = {};
#pragma unroll
    for (int fkr = 0; fkr < 4; ++fkr) {
      const int rb = t * 4 + fkr;
      s16x8 kf0 = *(const s16x8*)&Ksn[(size_t)(((rb * 8 + lg) * 16) + lx) * 8];
      s16x8 kf1 = *(const s16x8*)&Ksn[(size_t)(((rb * 8 + 4 + lg) * 16) + lx) * 8];
#pragma unroll
      for (int fq = 0; fq < 4; ++fq) {
        s[fkr][fq] = MFMA32(kf0, qf[fq][0], s[fkr][fq]);
        s[fkr][fq] = MFMA32(kf1, qf[fq][1], s[fkr][fq]);
      }
    }

    // V A-frags hoisted; L2 latency hides under softmax
    uint2 vraw[8][2];
#pragma unroll
    for (int kb = 0; kb < 2; ++kb)
#pragma unroll
      for (int fd = 0; fd < 4; ++fd) {
        const int d = fd * 16 + lx;
        const int g0 = (kt >> 2) + kb * 8 + lg * 2;
        const uint2* vp = (const uint2*)&Vsn[(((size_t)g0) * 64 + d) * 4];
        vraw[kb * 4 + fd][0] = vp[0];
        vraw[kb * 4 + fd][1] = vp[64];  // g0+1
      }

    // additive mask fill (broadcast float4 from L2)
    float4 fl[4];
#pragma unroll
    for (int fkr = 0; fkr < 4; ++fkr)
      fl[fkr] = *(const float4*)&kfp[kt + fkr * 16 + lg * 4];

    // softmax: p = exp2(s + fill); l-accumulate; pack P^T into swizzled LDS
#pragma unroll
    for (int fq = 0; fq < 4; ++fq) {
#pragma unroll
      for (int fkr = 0; fkr < 4; ++fkr) {
        float p0 = __builtin_amdgcn_exp2f(s[fkr][fq][0] + fl[fkr].x);
        float p1 = __builtin_amdgcn_exp2f(s[fkr][fq][1] + fl[fkr].y);
        float p2 = __builtin_amdgcn_exp2f(s[fkr][fq][2] + fl[fkr].z);
        float p3 = __builtin_amdgcn_exp2f(s[fkr][fq][3] + fl[fkr].w);
        lrun[fq] += (p0 + p1) + (p2 + p3);
        const int row = wave * 64 + fq * 16 + lx;
        const int chunk = fkr * 2 + (lg >> 1);
        unsigned short* wp = &PT[row][((chunk ^ sw) << 3) + ((lg & 1) << 2)];
        uint2 pd;
        pd.x = cvtpk(p0, p1);
        pd.y = cvtpk(p2, p3);
        *(uint2*)wp = pd;
      }
    }
    asm volatile("s_waitcnt lgkmcnt(0)" ::: "memory");
    __builtin_amdgcn_sched_barrier(0);

    // PV: O^T[d][q] += V^T[d][lk] * P^T[lk][q]  (wave-private PT rows)
#pragma unroll
    for (int kb = 0; kb < 2; ++kb) {
      s16x8 pf[4];
#pragma unroll
      for (int fq = 0; fq < 4; ++fq)
        pf[fq] = *(const s16x8*)&PT[wave * 64 + fq * 16 + lx][((kb * 4 + lg) ^ sw) << 3];
#pragma unroll
      for (int fd = 0; fd < 4; ++fd) {
        union { uint2 u2[2]; s16x8 v; } vf;
        vf.u2[0] = vraw[kb * 4 + fd][0];
        vf.u2[1] = vraw[kb * 4 + fd][1];
#pragma unroll
        for (int fq = 0; fq < 4; ++fq)
          o[fd][fq] = MFMA32(vf.v, pf[fq], o[fd][fq]);
      }
    }
  }

  // epilogue: l-reduce over lg groups, scale by qmask/l, store bf16
#pragma unroll
  for (int fq = 0; fq < 4; ++fq) {
    lrun[fq] += __shfl_xor(lrun[fq], 16);
    lrun[fq] += __shfl_xor(lrun[fq], 32);
  }
#pragma unroll
  for (int fd = 0; fd < 4; ++fd)
#pragma unroll
    for (int fq = 0; fq < 4; ++fq) {
      const int qg = qw + fq * 16 + lx;
      const float osc = qmask[b * 2048 + qg] / lrun[fq];
      *(u16x4*)&attnw[((size_t)(b * 2048 + qg)) * 768 + h * 64 + fd * 16 + lg * 4] =
          pack4(o[fd][fq][0] * osc, o[fd][fq][1] * osc, o[fd][fq][2] * osc,
                o[fd][fq][3] * osc);
    }
}

// ---------------------------------------------------------------------------
// Residual + LayerNorm (ddof=1), vectorized: 192 threads x float4.
// ---------------------------------------------------------------------------
__global__ __launch_bounds__(192) void ln_kernel(
    const unsigned short* __restrict__ attnw, const float* __restrict__ query,
    const float* __restrict__ gamma, const float* __restrict__ beta,
    float* __restrict__ out) {
  const int row = blockIdx.x, tid = threadIdx.x;
  const size_t base = (size_t)row * 768 + tid * 4;
  u16x4 aw = *(const u16x4*)&attnw[base];
  float4 q = *(const float4*)&query[base];
  float x0 = bf2f(aw[0]) + q.x;
  float x1 = bf2f(aw[1]) + q.y;
  float x2 = bf2f(aw[2]) + q.z;
  float x3 = bf2f(aw[3]) + q.w;
  float s = (x0 + x1) + (x2 + x3);
  float s2 = (x0 * x0 + x1 * x1) + (x2 * x2 + x3 * x3);
#pragma unroll
  for (int off = 1; off < 64; off <<= 1) {
    s += __shfl_xor(s, off);
    s2 += __shfl_xor(s2, off);
  }
  __shared__ float ws[3], ws2[3];
  if ((tid & 63) == 0) { ws[tid >> 6] = s; ws2[tid >> 6] = s2; }
  __syncthreads();
  s = ws[0] + ws[1] + ws[2];
  s2 = ws2[0] + ws2[1] + ws2[2];
  const float mean = s * (1.0f / 768.0f);
  const float var = (s2 - 768.0f * mean * mean) * (1.0f / 767.0f);
  const float rstd = rsqrtf(var + 1e-5f);
  const float4 g = *(const float4*)&gamma[tid * 4];
  const float4 bt = *(const float4*)&beta[tid * 4];
  float4 r;
  r.x = g.x * (x0 - mean) * rstd + bt.x;
  r.y = g.y * (x1 - mean) * rstd + bt.y;
  r.z = g.z * (x2 - mean) * rstd + bt.z;
  r.w = g.w * (x3 - mean) * rstd + bt.w;
  *(float4*)&out[base] = r;
}

// ---------------------------------------------------------------------------
extern "C" void kernel_launch(void* const* d_in, const int* in_sizes, int n_in,
                              void* d_out, int out_size, void* d_ws, size_t ws_size,
                              hipStream_t stream) {
  const float* query = (const float*)d_in[0];
  const float* key = (const float*)d_in[1];
  const float* Wq = (const float*)d_in[2];
  const float* bq = (const float*)d_in[3];
  const float* Wk = (const float*)d_in[4];
  const float* bk = (const float*)d_in[5];
  const float* Wv = (const float*)d_in[6];
  const float* bv = (const float*)d_in[7];
  const float* gamma = (const float*)d_in[8];
  const float* beta = (const float*)d_in[9];
  float* out = (float*)d_out;

  unsigned short* Qbf = (unsigned short*)d_ws;
  unsigned short* Kbf = Qbf + 6291456;
  unsigned short* Qh = Kbf + 6291456;
  unsigned short* Ks = Qh + 6291456;
  unsigned short* Vs = Ks + 6291456;
  unsigned short* Wbf = Vs + 6291456;          // 1769472 shorts
  unsigned short* attnw = Qbf;                 // alias: Qbf dead after proj
  float* qmask = (float*)(Wbf + 1769472);
  float* kmaskF = qmask + 8192;

  convw<<<dim3(576, 3), 256, 0, stream>>>(Wq, Wk, Wv, Wbf);
  prepass<<<dim3(8192, 2), 192, 0, stream>>>(query, key, Qbf, Kbf, qmask, kmaskF);
  proj_qkv<<<2304, 256, 0, stream>>>(Qbf, Kbf, Wbf, bq, bk, bv, Qh, Ks, Vs);
  attn_fwd<<<768, 128, 0, stream>>>(Qh, Ks, Vs, qmask, kmaskF, attnw);
  ln_kernel<<<8192, 192, 0, stream>>>(attnw, query, gamma, beta, out);
}